// Round 9
// baseline (474.045 us; speedup 1.0000x reference)
//
#include <hip/hip_runtime.h>

#define N_NODES 100000
#define N_EDGES 500000
#define D 256
#define CAP 32          // bucket capacity per (node, relation); λ=5 ⇒ P(deg>32)≈1e-15

typedef __bf16 bf16x8 __attribute__((ext_vector_type(8)));
typedef float  f32x4  __attribute__((ext_vector_type(4)));
typedef unsigned int u32x2 __attribute__((ext_vector_type(2)));  // nontemporal-compatible

// ---- bf16 helpers (manual, RNE) -------------------------------------------
__device__ __forceinline__ unsigned short f2bf(float f) {
    unsigned int u = __float_as_uint(f);
    u += 0x7fffu + ((u >> 16) & 1u);
    return (unsigned short)(u >> 16);
}
__device__ __forceinline__ float bf2f(unsigned short b) {
    return __uint_as_float(((unsigned int)b) << 16);
}

// ---------------------------------------------------------------------------
// Prep kernel, WAVE-granular role interleave (round-7 win: heterogeneous
// waves co-resident per m114 overlap; block-range ordering serialized).
// Of every 22 waves: 16 convert, 5 bucket, 1 W-prep.
// ---------------------------------------------------------------------------
#define PREP_BLOCKS 17188   // ceil(22*3125 waves / 4 per block)

__global__ __launch_bounds__(256) void prep_kernel(
    const float* __restrict__ x, unsigned short* __restrict__ xb,
    const float* __restrict__ Ws, const float* __restrict__ W1,
    const float* __restrict__ W2, unsigned short* __restrict__ Wt,
    const int* __restrict__ src1, const int* __restrict__ dst1,
    const int* __restrict__ src2, const int* __restrict__ dst2,
    int* __restrict__ cnt1, int* __restrict__ cnt2,
    int* __restrict__ bkt1, int* __restrict__ bkt2)
{
    const int wid  = blockIdx.x * 4 + (threadIdx.x >> 6);  // global wave id
    const int lane = threadIdx.x & 63;
    const int group = wid / 22;
    const int pos   = wid - group * 22;

    if (pos < 16) {
        // ---- convert role: x fp32 -> xb bf16, 8 elems/lane, coalesced ----
        int cw = group * 16 + pos;
        if (cw >= 50000) return;
        size_t i = (size_t)cw * 512 + (size_t)lane * 8;
        float4 a = *(const float4*)(x + i);
        float4 c = *(const float4*)(x + i + 4);
        union { unsigned short s[8]; uint4 u; } o;
        o.s[0] = f2bf(a.x); o.s[1] = f2bf(a.y); o.s[2] = f2bf(a.z); o.s[3] = f2bf(a.w);
        o.s[4] = f2bf(c.x); o.s[5] = f2bf(c.y); o.s[6] = f2bf(c.z); o.s[7] = f2bf(c.w);
        *(uint4*)(xb + i) = o.u;
    } else if (pos < 21) {
        // ---- bucket role: 1 edge/lane, cnt/bkt atomics (L2-resident) ----
        int bw = group * 5 + (pos - 16);
        int e = bw * 64 + lane;
        if (e >= 2 * N_EDGES) return;
        bool r2 = (e >= N_EDGES);
        const int* src = r2 ? src2 : src1;
        const int* dst = r2 ? dst2 : dst1;
        int* cnt = r2 ? cnt2 : cnt1;
        int* bkt = r2 ? bkt2 : bkt1;
        int ei = r2 ? e - N_EDGES : e;
        int s = src[ei], d = dst[ei];
        int p = atomicAdd(&cnt[d], 1);
        if (p < CAP) bkt[d * CAP + p] = s;
    } else {
        // ---- W-prep role: Wt[n][k] = bf16(scale_k * W[k%256][n]) ----
        int idx = group * 64 + lane;
        if (idx >= 3 * D * D) return;
        int k = idx >> 8;
        int n = idx & (D - 1);
        const float* W = (k < D) ? Ws : (k < 2 * D ? W1 : W2);
        float scale = (k < D) ? 1.1f : 1.0f;
        Wt[(size_t)n * (3 * D) + k] = f2bf(W[(size_t)(k & (D - 1)) * D + n] * scale);
    }
}

// ---------------------------------------------------------------------------
// Gather: one wave per (node, relation). Chunk-8 preload (8 independent 512B
// row-reads in flight), wave-uniform predicated accumulate, rare tail loop.
// xa writes NON-TEMPORAL (keep xb resident in L3).
// ---------------------------------------------------------------------------
__global__ __launch_bounds__(256) void gather_kernel(
    const unsigned short* __restrict__ xb,
    const int* __restrict__ cnt1, const int* __restrict__ cnt2,
    const int* __restrict__ bkt1, const int* __restrict__ bkt2,
    unsigned short* __restrict__ xa1, unsigned short* __restrict__ xa2)
{
    long long gid = (long long)blockIdx.x * blockDim.x + threadIdx.x;
    int w = (int)(gid >> 6);
    int lane = (int)(gid & 63);
    if (w >= 2 * N_NODES) return;
    int node = w >> 1;
    int rel  = w & 1;

    const int* cnt = rel ? cnt2 : cnt1;
    const int* bkt = rel ? bkt2 : bkt1;
    unsigned short* xa = rel ? xa2 : xa1;

    int c = cnt[node]; if (c > CAP) c = CAP;
    int sid = (lane < c) ? bkt[(size_t)node * CAP + lane] : 0;

    ushort4 v[8];
    #pragma unroll
    for (int t = 0; t < 8; ++t) {
        int s = __shfl(sid, t);
        v[t] = *(const ushort4*)(xb + (size_t)s * D + lane * 4);
    }

    float a0 = 0.f, a1 = 0.f, a2 = 0.f, a3 = 0.f;
    #pragma unroll
    for (int t = 0; t < 8; ++t) {
        if (t < c) {   // wave-uniform predicate (scalar branch)
            a0 += bf2f(v[t].x); a1 += bf2f(v[t].y);
            a2 += bf2f(v[t].z); a3 += bf2f(v[t].w);
        }
    }
    for (int e = 8; e < c; ++e) {
        int s = __shfl(sid, e);
        ushort4 t = *(const ushort4*)(xb + (size_t)s * D + lane * 4);
        a0 += bf2f(t.x); a1 += bf2f(t.y); a2 += bf2f(t.z); a3 += bf2f(t.w);
    }

    u32x2 o;
    o.x = (unsigned)f2bf(a0) | ((unsigned)f2bf(a1) << 16);
    o.y = (unsigned)f2bf(a2) | ((unsigned)f2bf(a3) << 16);
    __builtin_nontemporal_store(o, (u32x2*)(xa + (size_t)node * D + lane * 4));
}

// ---------------------------------------------------------------------------
// MFMA GEMM: out = relu( [xb | xa1 | xa2] @ Wt^T + bias ), bf16 in, fp32 acc.
// M=100000, N=256, K=768.
// Round-9 restructure: rounds 7/8 both plateaued at 106.7 µs regardless of
// LDS scheme — BK=32 staging reads 64B of every 512B A-row (strided DRAM,
// 740 GB/s). Fix: stage a FULL 128x512B A-segment (64 KB) contiguously per
// seg (coalesced streaming), 8 barrier-free inner K-steps against it; B
// fragments load DIRECTLY from L2-resident Wt (393 KB) — no B staging, no
// inner barriers (6 barriers/block total vs 48).
// LDS chunk swizzle c^(row&7): write phase 32 consecutive chunks/row =
// conflict-free; read phase 16 lanes -> 8 pos-clusters x 2 = 2-way = free.
// ---------------------------------------------------------------------------
__global__ __launch_bounds__(512) void gemm_kernel(
    const unsigned short* __restrict__ xb,
    const unsigned short* __restrict__ xa1,
    const unsigned short* __restrict__ xa2,
    const unsigned short* __restrict__ Wt,   // [256 n][768 k] bf16, pre-scaled
    const float* __restrict__ bias, float* __restrict__ out)
{
    __shared__ unsigned short Alds[128 * 256];   // 64 KB, chunk-swizzled

    const int tid  = threadIdx.x;
    const int lane = tid & 63;
    const int wave = tid >> 6;          // 0..7
    const int quad = lane >> 4;
    const int l15  = lane & 15;
    const int m0 = blockIdx.x * 128;
    const int wm = (wave >> 2) * 64;    // 2 m-tiles x 4 n-tiles of 64
    const int wn = (wave & 3) * 64;

    const unsigned short* Aseg[3] = {xb, xa1, xa2};

    // Direct-from-L2 B fragment bases: lane l15 <-> n, quad <-> 8-k chunk.
    int bbase[4];
    #pragma unroll
    for (int j = 0; j < 4; ++j)
        bbase[j] = (wn + j * 16 + l15) * (3 * D) + quad * 8;

    // Staging geometry: 4096 16B-slots, 8 per thread; idx = s*512 + tid ->
    // row = idx>>5, chunk c = idx&31 (consecutive lanes = consecutive 16B).
    const int rowS = tid >> 5;          // row base for s=0 (advances 16/s)
    const int cS   = tid & 31;

    f32x4 acc[4][4] = {};

    for (int seg = 0; seg < 3; ++seg) {
        const unsigned short* __restrict__ A = Aseg[seg];

        #pragma unroll
        for (int s = 0; s < 8; ++s) {
            int row = rowS + s * 16;
            int m = m0 + row; if (m >= N_NODES) m = N_NODES - 1;  // junk rows dropped in epilogue
            uint4 v = *(const uint4*)(A + (size_t)m * D + cS * 8);
            *(uint4*)(Alds + row * 256 + ((cS ^ (row & 7)) * 8)) = v;
        }
        __syncthreads();

        #pragma unroll
        for (int kin = 0; kin < 8; ++kin) {
            const int kt = seg * 8 + kin;
            bf16x8 af[4], bfr[4];
            #pragma unroll
            for (int i = 0; i < 4; ++i) {
                int row = wm + i * 16 + l15;
                af[i] = *(const bf16x8*)(Alds + row * 256 +
                                         (((kin * 4 + quad) ^ (row & 7)) * 8));
            }
            #pragma unroll
            for (int j = 0; j < 4; ++j)
                bfr[j] = *(const bf16x8*)(Wt + bbase[j] + kt * 32);
            #pragma unroll
            for (int i = 0; i < 4; ++i)
                #pragma unroll
                for (int j = 0; j < 4; ++j)
                    acc[i][j] = __builtin_amdgcn_mfma_f32_16x16x32_bf16(
                        af[i], bfr[j], acc[i][j], 0, 0, 0);
        }
        __syncthreads();
    }

    // Epilogue: D layout col=lane&15, row=quad*4+reg (m89/m91 verified).
    #pragma unroll
    for (int j = 0; j < 4; ++j) {
        int col = wn + j * 16 + l15;
        float bj = bias[col];
        #pragma unroll
        for (int i = 0; i < 4; ++i) {
            int rb = m0 + wm + i * 16 + quad * 4;
            #pragma unroll
            for (int r = 0; r < 4; ++r) {
                int m = rb + r;
                if (m < N_NODES)
                    __builtin_nontemporal_store(
                        fmaxf(acc[i][j][r] + bj, 0.f),
                        out + (size_t)m * D + col);
            }
        }
    }
}

extern "C" void kernel_launch(void* const* d_in, const int* in_sizes, int n_in,
                              void* d_out, int out_size, void* d_ws, size_t ws_size,
                              hipStream_t stream) {
    const float* x    = (const float*)d_in[0];
    const float* Ws   = (const float*)d_in[1];
    const float* W1   = (const float*)d_in[2];
    const float* W2   = (const float*)d_in[3];
    const float* bias = (const float*)d_in[4];
    const int* src1   = (const int*)d_in[5];
    const int* dst1   = (const int*)d_in[6];
    const int* src2   = (const int*)d_in[7];
    const int* dst2   = (const int*)d_in[8];
    float* out = (float*)d_out;

    // Workspace layout (total 180.4 MB):
    char* p = (char*)d_ws;
    unsigned short* xb  = (unsigned short*)p; p += (size_t)N_NODES * D * 2;  // 51.2 MB
    unsigned short* xa1 = (unsigned short*)p; p += (size_t)N_NODES * D * 2;  // 51.2 MB
    unsigned short* xa2 = (unsigned short*)p; p += (size_t)N_NODES * D * 2;  // 51.2 MB
    int* cnt1 = (int*)p; p += (size_t)N_NODES * 4;                           // 0.4 MB
    int* cnt2 = (int*)p; p += (size_t)N_NODES * 4;                           // 0.4 MB
    int* bkt1 = (int*)p; p += (size_t)N_NODES * CAP * 4;                     // 12.8 MB
    int* bkt2 = (int*)p; p += (size_t)N_NODES * CAP * 4;                     // 12.8 MB
    unsigned short* Wt = (unsigned short*)p;                                 // 0.39 MB

    (void)hipMemsetAsync(cnt1, 0, (size_t)2 * N_NODES * 4, stream);

    prep_kernel<<<PREP_BLOCKS, 256, 0, stream>>>(
        x, xb, Ws, W1, W2, Wt, src1, dst1, src2, dst2, cnt1, cnt2, bkt1, bkt2);

    {   // gather-aggregate, one wave per (node, relation)
        long long total = (long long)2 * N_NODES * 64;
        gather_kernel<<<(int)((total + 255) / 256), 256, 0, stream>>>(
            xb, cnt1, cnt2, bkt1, bkt2, xa1, xa2);
    }
    {   // MFMA GEMM + bias + relu, full-N blocks
        gemm_kernel<<<(N_NODES + 127) / 128, 512, 0, stream>>>(
            xb, xa1, xa2, Wt, bias, out);
    }
}